// Round 4
// baseline (111.423 us; speedup 1.0000x reference)
//
#include <hip/hip_runtime.h>
#include <stdint.h>

#define DIM     300
#define NBATCH  4096
#define RTOK    32
#define NSUP    64      // N*S = 2*32 support cols
#define KP      320     // K padded to 10*32
#define NKS     10      // K steps of 32
#define ASTRIDE 328     // LDS row stride (ushort) for A tiles (16B-aligned rows)
#define SMST    82      // padded sm tile x-stride (floats)
#define SMY     36      // per-channel y extent (34 used + 2 pad)

typedef float f32x4 __attribute__((ext_vector_type(4)));
typedef short s16x8 __attribute__((ext_vector_type(8)));

static __device__ __forceinline__ unsigned bc(float x) { return __builtin_bit_cast(unsigned, x); }
static __device__ __forceinline__ float asf(unsigned u) { return __builtin_bit_cast(float, u); }
static __device__ __forceinline__ unsigned perm_hi(unsigned a, unsigned b) {
    return __builtin_amdgcn_perm(a, b, 0x07060302u);   // [a.hi16 : b.hi16]
}
static __device__ __forceinline__ unsigned short f2bf(float x) {   // RNE (prep only)
    unsigned u = bc(x);
    return (unsigned short)((u + 0x7FFFu + ((u >> 16) & 1u)) >> 16);
}
static __device__ __forceinline__ float bf2f(unsigned short h) { return asf((unsigned)h << 16); }

// ---------------- kernel 1: normalize support vectors -> bf16 hi/lo [64][320]
__global__ __launch_bounds__(64) void prep_kernel(
    const int* __restrict__ sidx, const float* __restrict__ emb,
    unsigned short* __restrict__ Bh, unsigned short* __restrict__ Bl) {
    const int j = blockIdx.x, l = threadIdx.x;
    const size_t tok = (size_t)sidx[j];
    const float* src = emb + tok * DIM;
    float e[5];
    #pragma unroll
    for (int c = 0; c < 5; ++c) {
        const int k = c * 64 + l;
        e[c] = (k < DIM) ? src[k] : 0.f;
    }
    float s = e[0]*e[0] + e[1]*e[1] + e[2]*e[2] + e[3]*e[3] + e[4]*e[4];
    #pragma unroll
    for (int m = 32; m >= 1; m >>= 1) s += __shfl_xor(s, m);
    const float rn = 1.f / fmaxf(sqrtf(s), 1e-8f);
    #pragma unroll
    for (int c = 0; c < 5; ++c) {
        const int k = c * 64 + l;                 // always < 320
        const float v = (k < DIM) ? e[c] * rn : 0.f;
        const unsigned short h = f2bf(v);
        Bh[j * KP + k] = h;
        Bl[j * KP + k] = f2bf(v - bf2f(h));
    }
}

// ---------------- kernel 2: fused gather + split-bf16 MFMA GEMM (+Gram norms) + tail
__global__ __launch_bounds__(512, 4) void main_kernel(
    const int* __restrict__ tokens, const float* __restrict__ emb,
    const unsigned short* __restrict__ Bh, const unsigned short* __restrict__ Bl,
    const float* __restrict__ c1w, const float* __restrict__ c1b,
    const float* __restrict__ c2w, const float* __restrict__ c2b,
    const float* __restrict__ f2w, const float* __restrict__ f2b,
    const float* __restrict__ fcw, const float* __restrict__ fcb,
    float* __restrict__ out) {

    __shared__ __attribute__((aligned(16))) unsigned short Ah[32 * ASTRIDE];
    __shared__ __attribute__((aligned(16))) unsigned short Al[32 * ASTRIDE];
    __shared__ __attribute__((aligned(16))) float smP[34 * SMST];  // [xp=r+1][ch][yp=s+1]
    __shared__ __attribute__((aligned(16))) float norms[32];
    __shared__ float scr[2];
    float* pl1P = (float*)Ah;   // overlay: [2][17][18] zero-bordered pool1

    const int tid = threadIdx.x;
    const int w = tid >> 6, l = tid & 63;
    const int batch = blockIdx.x;
    const int cb = (w & 3) * 16, rb = (w >> 2) * 16;
    const int c = l & 15;

    // ---- P0a: issue gather loads (HBM, ~900cy) first
    const int row0 = w * 4;
    const bool tl = (l < DIM - 256);          // tail lanes 0..43
    float4 e4[4]; float et[4];
    #pragma unroll
    for (int rr = 0; rr < 4; ++rr) {
        const size_t tok = (size_t)tokens[batch * RTOK + row0 + rr];
        const float* src = emb + tok * DIM;
        e4[rr] = *(const float4*)(src + 4 * l);
        et[rr] = tl ? src[256 + l] : 0.f;
    }

    // ---- P0b: prefetch this wave's B columns into registers (L2-hot, overlaps gather)
    s16x8 rbh[NKS], rbl[NKS];
    {
        const int boff = (cb + c) * KP + (l >> 4) * 8;
        #pragma unroll
        for (int t = 0; t < NKS; ++t) {
            rbh[t] = *(const s16x8*)(Bh + boff + t * 32);
            rbl[t] = *(const s16x8*)(Bl + boff + t * 32);
        }
    }

    // ---- P0c: clear smP while loads fly (697 float4 chunks)
    {
        const f32x4 z = {0.f, 0.f, 0.f, 0.f};
        ((f32x4*)smP)[tid] = z;
        if (tid < 697 - 512) ((f32x4*)smP)[512 + tid] = z;
    }

    // ---- P0d: pack gathered rows to split-bf16, store A tiles
    #pragma unroll
    for (int rr = 0; rr < 4; ++rr) {
        const int row = row0 + rr;
        // round-half-up hi (lo captures the rounding error exactly)
        const unsigned u0 = bc(e4[rr].x) + 0x8000u, u1 = bc(e4[rr].y) + 0x8000u;
        const unsigned u2 = bc(e4[rr].z) + 0x8000u, u3 = bc(e4[rr].w) + 0x8000u;
        const float r0 = e4[rr].x - asf(u0 & 0xffff0000u);
        const float r1 = e4[rr].y - asf(u1 & 0xffff0000u);
        const float r2 = e4[rr].z - asf(u2 & 0xffff0000u);
        const float r3 = e4[rr].w - asf(u3 & 0xffff0000u);
        const unsigned h01 = perm_hi(u1, u0), h23 = perm_hi(u3, u2);
        const unsigned l01 = perm_hi(bc(r1) + 0x8000u, bc(r0) + 0x8000u);
        const unsigned l23 = perm_hi(bc(r3) + 0x8000u, bc(r2) + 0x8000u);
        *(uint2*)(&Ah[row * ASTRIDE + 4 * l]) = uint2{h01, h23};
        *(uint2*)(&Al[row * ASTRIDE + 4 * l]) = uint2{l01, l23};
        const unsigned ut = bc(et[rr]) + 0x8000u;
        const float rt = et[rr] - asf(ut & 0xffff0000u);
        Ah[row * ASTRIDE + 256 + l] = (unsigned short)(ut >> 16);
        Al[row * ASTRIDE + 256 + l] = (unsigned short)((bc(rt) + 0x8000u) >> 16);
    }
    __syncthreads();   // BAR1

    // ---- P1: MFMA GEMM + Gram-diag row norms; wave w -> rows rb.., cols cb..
    {
        const int abase = (rb + c) * ASTRIDE + (l >> 4) * 8;
        f32x4 a0 = {0,0,0,0}, a1 = {0,0,0,0}, a2 = {0,0,0,0};
        f32x4 gv = {0,0,0,0}, g2 = {0,0,0,0};
        #pragma unroll
        for (int t = 0; t < NKS; ++t) {
            const s16x8 ah = *(const s16x8*)(Ah + abase + t * 32);
            const s16x8 al = *(const s16x8*)(Al + abase + t * 32);
            a0 = __builtin_amdgcn_mfma_f32_16x16x32_bf16(ah, rbh[t], a0, 0, 0, 0);
            a1 = __builtin_amdgcn_mfma_f32_16x16x32_bf16(ah, rbl[t], a1, 0, 0, 0);
            a2 = __builtin_amdgcn_mfma_f32_16x16x32_bf16(al, rbh[t], a2, 0, 0, 0);
            gv = __builtin_amdgcn_mfma_f32_16x16x32_bf16(ah, ah, gv, 0, 0, 0);
            g2 = __builtin_amdgcn_mfma_f32_16x16x32_bf16(ah, al, g2, 0, 0, 0);
        }
        // diagonal lanes write |x_row|^2 (twin waves race with identical values)
        if ((l >> 4) == (c >> 2)) {
            const int q = c & 3;
            const float d1 = (q == 0) ? gv[0] : (q == 1) ? gv[1] : (q == 2) ? gv[2] : gv[3];
            const float d2 = (q == 0) ? g2[0] : (q == 1) ? g2[1] : (q == 2) ? g2[2] : g2[3];
            norms[rb + c] = d1 + 2.f * d2;
        }
        asm volatile("s_waitcnt lgkmcnt(0)" ::: "memory");   // intra-wave LDS write->read
        const f32x4 n4 = *(const f32x4*)&norms[rb + (l >> 4) * 4];
        const int col = cb + c, ch = col >> 5, s = col & 31;
        #pragma unroll
        for (int q = 0; q < 4; ++q) {
            const float rn = __builtin_amdgcn_rcpf(
                fmaxf(__builtin_amdgcn_sqrtf(n4[q]), 1e-8f));
            const int row = rb + (l >> 4) * 4 + q;
            smP[(row + 1) * SMST + ch * SMY + (s + 1)] = (a0[q] + a1[q] + a2[q]) * rn;
        }
    }
    __syncthreads();   // BAR2

    // ---- P2: softmax-pool (waves 0-1) + pl1 border zero + conv1 partials (all)
    if (w < 2) {        // channel w; lane covers row r = l&31, s-half l>>5
        const int r = l & 31, hf = l >> 5;
        const float* bp = &smP[(r + 1) * SMST + w * SMY + 1 + hf * 16];
        float se = 0.f, sv = 0.f;
        #pragma unroll
        for (int j = 0; j < 16; ++j) {
            const float v = bp[j];
            const float e = __expf(v);       // |v| <= 1: no max-shift needed
            se += e; sv = fmaf(e, v, sv);
        }
        #pragma unroll
        for (int m = 32; m >= 1; m >>= 1) { se += __shfl_xor(se, m); sv += __shfl_xor(sv, m); }
        if (l == 0) scr[w] = sv / se;
    }
    if (tid >= 446) {   // zero pl1P borders: yp=0 row (17) + xp=0 col (16), x2 channels
        const int z = tid - 446;
        const int ic = z / 33, rm = z % 33;
        pl1P[ic * 306 + (rm < 17 ? rm : (rm - 16) * 18)] = 0.f;
    }
    const int oc = tid >> 8, ii = (tid >> 4) & 15, jj = tid & 15;
    float pc[2][4] = {{0,0,0,0},{0,0,0,0}};
    #pragma unroll
    for (int ic = 0; ic < 2; ++ic) {
        float p[4][4];
        #pragma unroll
        for (int a = 0; a < 4; ++a) {        // xp = 2jj+a, yp base 2ii
            const int off = (2 * jj + a) * SMST + ic * SMY + 2 * ii;
            const float2 v01 = *(const float2*)&smP[off];
            const float2 v23 = *(const float2*)&smP[off + 2];
            p[a][0] = v01.x; p[a][1] = v01.y; p[a][2] = v23.x; p[a][3] = v23.y;
        }
        #pragma unroll
        for (int py = 0; py < 2; ++py)
        #pragma unroll
        for (int px = 0; px < 2; ++px)
        #pragma unroll
        for (int dy = 0; dy < 3; ++dy)
        #pragma unroll
        for (int dx = 0; dx < 3; ++dx)
            pc[ic][py * 2 + px] += c1w[(oc * 2 + ic) * 9 + dy * 3 + dx] * p[px + dx][py + dy];
    }
    __syncthreads();   // BAR3

    // ---- P3: gate + relu + maxpool -> pl1P
    {
        const float p0s = scr[0], p1s = scr[1];
        const float gg0 = 1.f / (1.f + __expf(-(f2w[0] * p0s + f2w[1] * p1s + f2b[0])));
        const float gg1 = 1.f / (1.f + __expf(-(f2w[2] * p0s + f2w[3] * p1s + f2b[1])));
        const float bias = c1b[oc];
        float mx = 0.f;    // relu folded: start at 0
        #pragma unroll
        for (int i = 0; i < 4; ++i)
            mx = fmaxf(mx, bias + gg0 * pc[0][i] + gg1 * pc[1][i]);
        pl1P[oc * 306 + (ii + 1) * 18 + (jj + 1)] = mx;
    }
    __syncthreads();   // BAR4

    // ---- P4: wave 0: conv2(2x2,pad1)+relu+avgpool2 + fc -> out
    if (w == 0) {
        float o0 = 0.f, o1 = 0.f;
        #pragma unroll
        for (int h = 0; h < 2; ++h) {
            const int o = h * 64 + l, oc2 = o >> 6, ii2 = (o >> 3) & 7, jj2 = o & 7;
            float sum = 0.f;
            #pragma unroll
            for (int py = 0; py < 2; ++py)
            #pragma unroll
            for (int px = 0; px < 2; ++px) {
                const int y = 2 * ii2 + py, x = 2 * jj2 + px;
                float acc = c2b[oc2];
                #pragma unroll
                for (int ic = 0; ic < 2; ++ic)
                #pragma unroll
                for (int dy = 0; dy < 2; ++dy)
                #pragma unroll
                for (int dx = 0; dx < 2; ++dx)
                    acc += c2w[((oc2 * 2 + ic) * 2 + dy) * 2 + dx] *
                           pl1P[ic * 306 + (y + dy) * 18 + (x + dx)];
                sum += fmaxf(acc, 0.f);
            }
            const float val = 0.25f * sum;
            o0 = fmaf(val, fcw[o], o0);
            o1 = fmaf(val, fcw[128 + o], o1);
        }
        #pragma unroll
        for (int m = 32; m >= 1; m >>= 1) { o0 += __shfl_xor(o0, m); o1 += __shfl_xor(o1, m); }
        if (l == 0) {
            out[batch * 2 + 0] = fcb[0] + o0;
            out[batch * 2 + 1] = fcb[1] + o1;
        }
    }
}

extern "C" void kernel_launch(void* const* d_in, const int* in_sizes, int n_in,
                              void* d_out, int out_size, void* d_ws, size_t ws_size,
                              hipStream_t stream) {
    const int* tokens = (const int*)d_in[0];
    const int* sidx   = (const int*)d_in[1];
    const float* emb  = (const float*)d_in[2];
    const float* c1w  = (const float*)d_in[3];
    const float* c1b  = (const float*)d_in[4];
    const float* c2w  = (const float*)d_in[5];
    const float* c2b  = (const float*)d_in[6];
    const float* f2w  = (const float*)d_in[7];
    const float* f2b  = (const float*)d_in[8];
    const float* fcw  = (const float*)d_in[9];
    const float* fcb  = (const float*)d_in[10];

    unsigned short* Bh = (unsigned short*)d_ws;
    unsigned short* Bl = Bh + NSUP * KP;

    prep_kernel<<<NSUP, 64, 0, stream>>>(sidx, emb, Bh, Bl);
    main_kernel<<<NBATCH, 512, 0, stream>>>(tokens, emb, Bh, Bl,
                                            c1w, c1b, c2w, c2b,
                                            f2w, f2b, fcw, fcb, (float*)d_out);
}